// Round 2
// baseline (94.606 us; speedup 1.0000x reference)
//
#include <hip/hip_runtime.h>
#include <hip/hip_bf16.h>

#define NB 32
#define NN 1024
#define IND 128
#define HD 64

typedef float f32x4 __attribute__((ext_vector_type(4)));
typedef short bf16x8 __attribute__((ext_vector_type(8)));
typedef unsigned short ushortx4 __attribute__((ext_vector_type(4)));

union FragU { unsigned short us[8]; bf16x8 v; };

__device__ __forceinline__ unsigned short f2bf(float f) {
    union { float f; unsigned u; } x; x.f = f;
    unsigned r = x.u + 0x7FFFu + ((x.u >> 16) & 1u);  // RNE
    return (unsigned short)(r >> 16);
}
__device__ __forceinline__ float bf2f(unsigned short h) {
    union { unsigned u; float f; } x; x.u = ((unsigned)h) << 16; return x.f;
}

// ---------------- kernel 0: weight prep (transpose + hi/lo bf16 split) ------
// WcT  [128 out][128 k] : out 0..63 = W_h cols, 64..127 = W_fc1 cols
// Wg1T/Wg2T [64 out][64 k]; biasP1[64] = b_g1 + b_g2
__global__ void prep_k(const float* __restrict__ W_h, const float* __restrict__ W_fc1,
                       const float* __restrict__ W_g1, const float* __restrict__ W_g2,
                       const float* __restrict__ b_g1, const float* __restrict__ b_g2,
                       unsigned short* __restrict__ WcT_hi, unsigned short* __restrict__ WcT_lo,
                       unsigned short* __restrict__ Wg1T_hi, unsigned short* __restrict__ Wg1T_lo,
                       unsigned short* __restrict__ Wg2T_hi, unsigned short* __restrict__ Wg2T_lo,
                       float* __restrict__ biasP1) {
    int t = blockIdx.x * blockDim.x + threadIdx.x;
    if (t < 16384) {
        int o = t >> 7, k = t & 127;
        float v = (o < 64) ? W_h[k * 64 + o] : W_fc1[k * 64 + (o - 64)];
        unsigned short hi = f2bf(v);
        WcT_hi[t] = hi; WcT_lo[t] = f2bf(v - bf2f(hi));
    } else if (t < 20480) {
        int r = t - 16384; int o = r >> 6, k = r & 63;
        float v = W_g1[k * 64 + o];
        unsigned short hi = f2bf(v);
        Wg1T_hi[r] = hi; Wg1T_lo[r] = f2bf(v - bf2f(hi));
    } else if (t < 24576) {
        int r = t - 20480; int o = r >> 6, k = r & 63;
        float v = W_g2[k * 64 + o];
        unsigned short hi = f2bf(v);
        Wg2T_hi[r] = hi; Wg2T_lo[r] = f2bf(v - bf2f(hi));
    } else if (t < 24640) {
        int j = t - 24576;
        biasP1[j] = b_g1[j] + b_g2[j];
    }
}

// ---------------- kernel 1: h (-> hT bf16), x_proj (f32), p1 ----------------
// grid 512 x 256; block = 64 rows of one batch; wave = 16 rows.
__global__ __launch_bounds__(256) void k1(
        const float* __restrict__ x,
        const unsigned short* __restrict__ WcT_hi, const unsigned short* __restrict__ WcT_lo,
        const unsigned short* __restrict__ Wg1T_hi, const unsigned short* __restrict__ Wg1T_lo,
        const float* __restrict__ b_h, const float* __restrict__ b_fc1,
        const float* __restrict__ biasP1,
        unsigned short* __restrict__ hT, float* __restrict__ xproj,
        float* __restrict__ p1) {
    __shared__ unsigned short lds_hi[64 * 64];
    __shared__ unsigned short lds_lo[64 * 64];

    const int tid = threadIdx.x;
    const int w = tid >> 6, lane = tid & 63;
    const int lr = lane & 15, lg = lane >> 4;
    const int blk = blockIdx.x;
    const int b = blk >> 4;
    const int n0 = (blk & 15) * 64;
    const int nw = n0 + w * 16;

    const float* xp = x + (size_t)(b * NN + nw + lr) * IND;

    f32x4 acc[8];
#pragma unroll
    for (int f = 0; f < 8; f++) acc[f] = (f32x4){0.f, 0.f, 0.f, 0.f};

#pragma unroll
    for (int ks = 0; ks < 4; ks++) {
        const f32x4* ap = (const f32x4*)(xp + 32 * ks + 8 * lg);
        f32x4 a0 = ap[0], a1 = ap[1];
        FragU ah, al;
#pragma unroll
        for (int i = 0; i < 4; i++) {
            unsigned short h0 = f2bf(a0[i]); ah.us[i] = h0;     al.us[i]     = f2bf(a0[i] - bf2f(h0));
            unsigned short h1 = f2bf(a1[i]); ah.us[4 + i] = h1; al.us[4 + i] = f2bf(a1[i] - bf2f(h1));
        }
#pragma unroll
        for (int f = 0; f < 8; f++) {
            int off = (16 * f + lr) * 128 + 32 * ks + 8 * lg;
            bf16x8 wh = *(const bf16x8*)(WcT_hi + off);
            bf16x8 wl = *(const bf16x8*)(WcT_lo + off);
            acc[f] = __builtin_amdgcn_mfma_f32_16x16x32_bf16(ah.v, wh, acc[f], 0, 0, 0);
            acc[f] = __builtin_amdgcn_mfma_f32_16x16x32_bf16(ah.v, wl, acc[f], 0, 0, 0);
            acc[f] = __builtin_amdgcn_mfma_f32_16x16x32_bf16(al.v, wh, acc[f], 0, 0, 0);
        }
    }

    const int nbase = nw + 4 * lg;

    // h (frags 0..3): + bias, store packed bf16 to hT[b][c][n]
#pragma unroll
    for (int f = 0; f < 4; f++) {
        int c = 16 * f + lr;
        float bh = b_h[c];
        ushortx4 hv;
#pragma unroll
        for (int r = 0; r < 4; r++) hv[r] = f2bf(acc[f][r] + bh);
        *(ushortx4*)(hT + (size_t)(b * 64 + c) * 1024 + nbase) = hv;
    }

    // x_proj (frags 4..7): f32 store + swizzled hi/lo bf16 to LDS
#pragma unroll
    for (int f = 4; f < 8; f++) {
        int c = 16 * (f - 4) + lr;
        float bp = b_fc1[c];
#pragma unroll
        for (int r = 0; r < 4; r++) {
            float v = acc[f][r] + bp;
            int n = nbase + r;
            xproj[(size_t)(b * NN + n) * 64 + c] = v;
            int ln = w * 16 + 4 * lg + r;
            int idx = ln * 64 + (((c >> 3) ^ (ln & 7)) << 3) + (c & 7);
            unsigned short hi = f2bf(v);
            lds_hi[idx] = hi;
            lds_lo[idx] = f2bf(v - bf2f(hi));
        }
    }
    __syncthreads();

    // p1 = x_proj @ W_g1 + (b_g1+b_g2), split precision
    f32x4 accP[4];
#pragma unroll
    for (int f = 0; f < 4; f++) accP[f] = (f32x4){0.f, 0.f, 0.f, 0.f};
#pragma unroll
    for (int ks = 0; ks < 2; ks++) {
        int ln = w * 16 + lr;
        int c0 = 32 * ks + 8 * lg;
        int idx = ln * 64 + (((c0 >> 3) ^ (ln & 7)) << 3);
        bf16x8 a_hi = *(const bf16x8*)(lds_hi + idx);
        bf16x8 a_lo = *(const bf16x8*)(lds_lo + idx);
#pragma unroll
        for (int f = 0; f < 4; f++) {
            int off = (16 * f + lr) * 64 + c0;
            bf16x8 b_hi = *(const bf16x8*)(Wg1T_hi + off);
            bf16x8 b_lo = *(const bf16x8*)(Wg1T_lo + off);
            accP[f] = __builtin_amdgcn_mfma_f32_16x16x32_bf16(a_hi, b_hi, accP[f], 0, 0, 0);
            accP[f] = __builtin_amdgcn_mfma_f32_16x16x32_bf16(a_hi, b_lo, accP[f], 0, 0, 0);
            accP[f] = __builtin_amdgcn_mfma_f32_16x16x32_bf16(a_lo, b_hi, accP[f], 0, 0, 0);
        }
    }
#pragma unroll
    for (int f = 0; f < 4; f++) {
        int c = 16 * f + lr;
        float bb = biasP1[c];
#pragma unroll
        for (int r = 0; r < 4; r++) {
            int n = nbase + r;
            p1[(size_t)(b * NN + n) * 64 + c] = accP[f][r] + bb;
        }
    }
}

// ---------------- kernel 2: x_new = A@h ; fused gate epilogue ---------------
__global__ __launch_bounds__(256) void k2(
        const float* __restrict__ A, const unsigned short* __restrict__ hT,
        const unsigned short* __restrict__ Wg2T_hi, const unsigned short* __restrict__ Wg2T_lo,
        const float* __restrict__ p1, const float* __restrict__ xproj,
        float* __restrict__ out) {
    __shared__ unsigned short ldsh[4 * 1024];
    __shared__ unsigned short ldsl[4 * 1024];

    const int tid = threadIdx.x;
    const int w = tid >> 6, lane = tid & 63;
    const int lr = lane & 15, lg = lane >> 4;
    const int blk = blockIdx.x;
    const int b = blk >> 4;
    const int n0 = (blk & 15) * 64;
    const int nw = n0 + w * 16;

    const float* Ap = A + (size_t)(b * NN + nw + lr) * NN;
    const unsigned short* hp = hT + (size_t)b * 64 * 1024;

    f32x4 acc[4];
#pragma unroll
    for (int f = 0; f < 4; f++) acc[f] = (f32x4){0.f, 0.f, 0.f, 0.f};

#pragma unroll 4
    for (int m = 0; m < NN; m += 32) {
        const f32x4* ap = (const f32x4*)(Ap + m + 8 * lg);
        f32x4 a0 = ap[0], a1 = ap[1];
        FragU au;
#pragma unroll
        for (int i = 0; i < 4; i++) { au.us[i] = f2bf(a0[i]); au.us[4 + i] = f2bf(a1[i]); }
#pragma unroll
        for (int f = 0; f < 4; f++) {
            bf16x8 bf = *(const bf16x8*)(hp + (16 * f + lr) * 1024 + m + 8 * lg);
            acc[f] = __builtin_amdgcn_mfma_f32_16x16x32_bf16(au.v, bf, acc[f], 0, 0, 0);
        }
    }

    // transpose x_new hi/lo (bf16) into per-wave swizzled LDS region
    unsigned short* wh = ldsh + w * 1024;
    unsigned short* wl = ldsl + w * 1024;
#pragma unroll
    for (int f = 0; f < 4; f++) {
        int c = 16 * f + lr;
#pragma unroll
        for (int r = 0; r < 4; r++) {
            int ln = 4 * lg + r;
            int idx = ln * 64 + (((c >> 3) ^ (ln & 7)) << 3) + (c & 7);
            float v = acc[f][r];
            unsigned short hi = f2bf(v);
            wh[idx] = hi;
            wl[idx] = f2bf(v - bf2f(hi));
        }
    }
    __syncthreads();

    // g2 = x_new @ W_g2, split precision
    f32x4 accG[4];
#pragma unroll
    for (int f = 0; f < 4; f++) accG[f] = (f32x4){0.f, 0.f, 0.f, 0.f};
#pragma unroll
    for (int ks = 0; ks < 2; ks++) {
        int c0 = 32 * ks + 8 * lg;
        int idx = lr * 64 + (((c0 >> 3) ^ (lr & 7)) << 3);
        bf16x8 a_hi = *(const bf16x8*)(wh + idx);
        bf16x8 a_lo = *(const bf16x8*)(wl + idx);
#pragma unroll
        for (int f = 0; f < 4; f++) {
            int off = (16 * f + lr) * 64 + c0;
            bf16x8 b_hi = *(const bf16x8*)(Wg2T_hi + off);
            bf16x8 b_lo = *(const bf16x8*)(Wg2T_lo + off);
            accG[f] = __builtin_amdgcn_mfma_f32_16x16x32_bf16(a_hi, b_hi, accG[f], 0, 0, 0);
            accG[f] = __builtin_amdgcn_mfma_f32_16x16x32_bf16(a_hi, b_lo, accG[f], 0, 0, 0);
            accG[f] = __builtin_amdgcn_mfma_f32_16x16x32_bf16(a_lo, b_hi, accG[f], 0, 0, 0);
        }
    }

    // fused epilogue: gate = sigmoid(p1 + g2); out = xnew*g + xproj*(1-g)
#pragma unroll
    for (int f = 0; f < 4; f++) {
        int c = 16 * f + lr;
#pragma unroll
        for (int r = 0; r < 4; r++) {
            int n = nw + 4 * lg + r;
            size_t g = (size_t)(b * NN + n) * 64 + c;
            float xnew = acc[f][r];
            float z = p1[g] + accG[f][r];
            float gate = 1.f / (1.f + __expf(-z));
            float xpv = xproj[g];
            out[g] = xnew * gate + xpv * (1.f - gate);
        }
    }
}

extern "C" void kernel_launch(void* const* d_in, const int* in_sizes, int n_in,
                              void* d_out, int out_size, void* d_ws, size_t ws_size,
                              hipStream_t stream) {
    const float* x     = (const float*)d_in[0];
    const float* A     = (const float*)d_in[1];
    const float* W_h   = (const float*)d_in[2];
    const float* b_h   = (const float*)d_in[3];
    const float* W_fc1 = (const float*)d_in[4];
    const float* b_fc1 = (const float*)d_in[5];
    const float* W_g1  = (const float*)d_in[6];
    const float* b_g1  = (const float*)d_in[7];
    const float* W_g2  = (const float*)d_in[8];
    const float* b_g2  = (const float*)d_in[9];
    float* out = (float*)d_out;

    char* ws = (char*)d_ws;
    unsigned short* WcT_hi  = (unsigned short*)(ws);            // 32 KB
    unsigned short* WcT_lo  = (unsigned short*)(ws + 32768);    // 32 KB
    unsigned short* Wg1T_hi = (unsigned short*)(ws + 65536);    // 8 KB
    unsigned short* Wg1T_lo = (unsigned short*)(ws + 73728);    // 8 KB
    unsigned short* Wg2T_hi = (unsigned short*)(ws + 81920);    // 8 KB
    unsigned short* Wg2T_lo = (unsigned short*)(ws + 90112);    // 8 KB
    float*          bP1     = (float*)(ws + 98304);             // 256 B
    unsigned short* hT      = (unsigned short*)(ws + 131072);                      // 4 MB
    float*          xprj    = (float*)(ws + 131072 + 4194304);                     // 8 MB
    float*          p1      = (float*)(ws + 131072 + 4194304 + 8388608);           // 8 MB

    prep_k<<<97, 256, 0, stream>>>(W_h, W_fc1, W_g1, W_g2, b_g1, b_g2,
                                   WcT_hi, WcT_lo, Wg1T_hi, Wg1T_lo, Wg2T_hi, Wg2T_lo, bP1);
    k1<<<512, 256, 0, stream>>>(x, WcT_hi, WcT_lo, Wg1T_hi, Wg1T_lo, b_h, b_fc1, bP1,
                                hT, xprj, p1);
    k2<<<512, 256, 0, stream>>>(A, hT, Wg2T_hi, Wg2T_lo, p1, xprj, out);
}

// Round 3
// 83.860 us; speedup vs baseline: 1.1281x; 1.1281x over previous
//
#include <hip/hip_runtime.h>
#include <hip/hip_bf16.h>

#define NB 32
#define NN 1024
#define IND 128
#define HD 64

typedef float f32x4 __attribute__((ext_vector_type(4)));
typedef short bf16x8 __attribute__((ext_vector_type(8)));
typedef unsigned short ushortx4 __attribute__((ext_vector_type(4)));

union FragU { unsigned short us[8]; bf16x8 v; };

__device__ __forceinline__ unsigned short f2bf(float f) {
    union { float f; unsigned u; } x; x.f = f;
    unsigned r = x.u + 0x7FFFu + ((x.u >> 16) & 1u);  // RNE
    return (unsigned short)(r >> 16);
}
__device__ __forceinline__ float bf2f(unsigned short h) {
    union { unsigned u; float f; } x; x.u = ((unsigned)h) << 16; return x.f;
}

// ---------------- kernel 0: weight prep (transpose + hi/lo bf16 split) ------
__global__ void prep_k(const float* __restrict__ W_h, const float* __restrict__ W_fc1,
                       const float* __restrict__ W_g1, const float* __restrict__ W_g2,
                       const float* __restrict__ b_g1, const float* __restrict__ b_g2,
                       unsigned short* __restrict__ WcT_hi, unsigned short* __restrict__ WcT_lo,
                       unsigned short* __restrict__ Wg1T_hi, unsigned short* __restrict__ Wg1T_lo,
                       unsigned short* __restrict__ Wg2T_hi, unsigned short* __restrict__ Wg2T_lo,
                       float* __restrict__ biasP1) {
    int t = blockIdx.x * blockDim.x + threadIdx.x;
    if (t < 16384) {
        int o = t >> 7, k = t & 127;
        float v = (o < 64) ? W_h[k * 64 + o] : W_fc1[k * 64 + (o - 64)];
        unsigned short hi = f2bf(v);
        WcT_hi[t] = hi; WcT_lo[t] = f2bf(v - bf2f(hi));
    } else if (t < 20480) {
        int r = t - 16384; int o = r >> 6, k = r & 63;
        float v = W_g1[k * 64 + o];
        unsigned short hi = f2bf(v);
        Wg1T_hi[r] = hi; Wg1T_lo[r] = f2bf(v - bf2f(hi));
    } else if (t < 24576) {
        int r = t - 20480; int o = r >> 6, k = r & 63;
        float v = W_g2[k * 64 + o];
        unsigned short hi = f2bf(v);
        Wg2T_hi[r] = hi; Wg2T_lo[r] = f2bf(v - bf2f(hi));
    } else if (t < 24640) {
        int j = t - 24576;
        biasP1[j] = b_g1[j] + b_g2[j];
    }
}

// ---------------- kernel 1: h (-> hT bf16), x_proj (f32), p1 ----------------
// grid 2048 x 64 threads; block = one 16-row strip, single wave.
__global__ __launch_bounds__(64) void k1(
        const float* __restrict__ x,
        const unsigned short* __restrict__ WcT_hi, const unsigned short* __restrict__ WcT_lo,
        const unsigned short* __restrict__ Wg1T_hi, const unsigned short* __restrict__ Wg1T_lo,
        const float* __restrict__ b_h, const float* __restrict__ b_fc1,
        const float* __restrict__ biasP1,
        unsigned short* __restrict__ hT, float* __restrict__ xproj,
        float* __restrict__ p1) {
    __shared__ unsigned short lds_hi[16 * 64];
    __shared__ unsigned short lds_lo[16 * 64];

    const int lane = threadIdx.x;
    const int lr = lane & 15, lg = lane >> 4;
    const int blk = blockIdx.x;
    const int b = blk >> 6;
    const int n0 = (blk & 63) * 16;

    const float* xp = x + (size_t)(b * NN + n0 + lr) * IND;

    // issue ALL x loads up-front (8 independent 16B loads)
    f32x4 xa[4][2];
#pragma unroll
    for (int ks = 0; ks < 4; ks++) {
        const f32x4* ap = (const f32x4*)(xp + 32 * ks + 8 * lg);
        xa[ks][0] = ap[0]; xa[ks][1] = ap[1];
    }

    f32x4 acc[8];
#pragma unroll
    for (int f = 0; f < 8; f++) acc[f] = (f32x4){0.f, 0.f, 0.f, 0.f};

#pragma unroll
    for (int ks = 0; ks < 4; ks++) {
        FragU ah, al;
#pragma unroll
        for (int i = 0; i < 4; i++) {
            unsigned short h0 = f2bf(xa[ks][0][i]); ah.us[i] = h0;     al.us[i]     = f2bf(xa[ks][0][i] - bf2f(h0));
            unsigned short h1 = f2bf(xa[ks][1][i]); ah.us[4 + i] = h1; al.us[4 + i] = f2bf(xa[ks][1][i] - bf2f(h1));
        }
#pragma unroll
        for (int f = 0; f < 8; f++) {
            int off = (16 * f + lr) * 128 + 32 * ks + 8 * lg;
            bf16x8 wh = *(const bf16x8*)(WcT_hi + off);
            bf16x8 wl = *(const bf16x8*)(WcT_lo + off);
            acc[f] = __builtin_amdgcn_mfma_f32_16x16x32_bf16(ah.v, wh, acc[f], 0, 0, 0);
            acc[f] = __builtin_amdgcn_mfma_f32_16x16x32_bf16(ah.v, wl, acc[f], 0, 0, 0);
            acc[f] = __builtin_amdgcn_mfma_f32_16x16x32_bf16(al.v, wh, acc[f], 0, 0, 0);
        }
    }

    const int nbase = n0 + 4 * lg;

    // h (frags 0..3): + bias, packed bf16 store to hT[b][c][n]
#pragma unroll
    for (int f = 0; f < 4; f++) {
        int c = 16 * f + lr;
        float bh = b_h[c];
        ushortx4 hv;
#pragma unroll
        for (int r = 0; r < 4; r++) hv[r] = f2bf(acc[f][r] + bh);
        *(ushortx4*)(hT + (size_t)(b * 64 + c) * 1024 + nbase) = hv;
    }

    // x_proj (frags 4..7): f32 store + swizzled hi/lo bf16 to LDS
#pragma unroll
    for (int f = 4; f < 8; f++) {
        int c = 16 * (f - 4) + lr;
        float bp = b_fc1[c];
#pragma unroll
        for (int r = 0; r < 4; r++) {
            float v = acc[f][r] + bp;
            int n = nbase + r;
            xproj[(size_t)(b * NN + n) * 64 + c] = v;
            int ln = 4 * lg + r;
            int idx = ln * 64 + (((c >> 3) ^ (ln & 7)) << 3) + (c & 7);
            unsigned short hi = f2bf(v);
            lds_hi[idx] = hi;
            lds_lo[idx] = f2bf(v - bf2f(hi));
        }
    }
    __syncthreads();

    // p1 = x_proj @ W_g1 + (b_g1+b_g2), split precision
    f32x4 accP[4];
#pragma unroll
    for (int f = 0; f < 4; f++) accP[f] = (f32x4){0.f, 0.f, 0.f, 0.f};
#pragma unroll
    for (int ks = 0; ks < 2; ks++) {
        int c0 = 32 * ks + 8 * lg;
        int idx = lr * 64 + (((c0 >> 3) ^ (lr & 7)) << 3);
        bf16x8 a_hi = *(const bf16x8*)(lds_hi + idx);
        bf16x8 a_lo = *(const bf16x8*)(lds_lo + idx);
#pragma unroll
        for (int f = 0; f < 4; f++) {
            int off = (16 * f + lr) * 64 + c0;
            bf16x8 b_hi = *(const bf16x8*)(Wg1T_hi + off);
            bf16x8 b_lo = *(const bf16x8*)(Wg1T_lo + off);
            accP[f] = __builtin_amdgcn_mfma_f32_16x16x32_bf16(a_hi, b_hi, accP[f], 0, 0, 0);
            accP[f] = __builtin_amdgcn_mfma_f32_16x16x32_bf16(a_hi, b_lo, accP[f], 0, 0, 0);
            accP[f] = __builtin_amdgcn_mfma_f32_16x16x32_bf16(a_lo, b_hi, accP[f], 0, 0, 0);
        }
    }
#pragma unroll
    for (int f = 0; f < 4; f++) {
        int c = 16 * f + lr;
        float bb = biasP1[c];
#pragma unroll
        for (int r = 0; r < 4; r++) {
            int n = nbase + r;
            p1[(size_t)(b * NN + n) * 64 + c] = accP[f][r] + bb;
        }
    }
}

// ---------------- kernel 2: x_new = A@h (K-split x4) ; fused gate epilogue --
// grid 2048 x 256; block = one 16-row strip; wave w takes K-quarter w.
__global__ __launch_bounds__(256, 8) void k2(
        const float* __restrict__ A, const unsigned short* __restrict__ hT,
        const unsigned short* __restrict__ Wg2T_hi, const unsigned short* __restrict__ Wg2T_lo,
        const float* __restrict__ p1, const float* __restrict__ xproj,
        float* __restrict__ out) {
    __shared__ float red[4 * 64 * 16];           // [wave][col][row] f32, 16 KB
    __shared__ unsigned short tile_hi[16 * 64];  // x_new bf16 hi, swizzled, 2 KB
    __shared__ unsigned short tile_lo[16 * 64];  // 2 KB

    const int tid = threadIdx.x;
    const int w = tid >> 6, lane = tid & 63;
    const int lr = lane & 15, lg = lane >> 4;
    const int blk = blockIdx.x;
    const int b = blk >> 6;
    const int n0 = (blk & 63) * 16;

    const float* Ap = A + (size_t)(b * NN + n0 + lr) * NN + w * 256;
    const unsigned short* hp = hT + (size_t)b * 64 * 1024 + w * 256;

    f32x4 acc[4];
#pragma unroll
    for (int f = 0; f < 4; f++) acc[f] = (f32x4){0.f, 0.f, 0.f, 0.f};

    // main loop over this wave's K-quarter, depth-1 A prefetch
    f32x4 c0 = *(const f32x4*)(Ap + 8 * lg);
    f32x4 c1 = *(const f32x4*)(Ap + 8 * lg + 4);
#pragma unroll
    for (int it = 0; it < 8; ++it) {
        const int m = it * 32;
        f32x4 p0, p1v;
        if (it < 7) {
            p0  = *(const f32x4*)(Ap + m + 32 + 8 * lg);
            p1v = *(const f32x4*)(Ap + m + 32 + 8 * lg + 4);
        }
        FragU au;
#pragma unroll
        for (int i = 0; i < 4; i++) { au.us[i] = f2bf(c0[i]); au.us[4 + i] = f2bf(c1[i]); }
#pragma unroll
        for (int f = 0; f < 4; f++) {
            bf16x8 bf = *(const bf16x8*)(hp + (16 * f + lr) * 1024 + m + 8 * lg);
            acc[f] = __builtin_amdgcn_mfma_f32_16x16x32_bf16(au.v, bf, acc[f], 0, 0, 0);
        }
        c0 = p0; c1 = p1v;
    }

    // write partials: red[w][col][row], f32x4 along rows
    {
        float* rp = red + w * 1024;
#pragma unroll
        for (int f = 0; f < 4; f++)
            *(f32x4*)(rp + (16 * f + lr) * 16 + 4 * lg) = acc[f];
    }
    __syncthreads();

    // each wave sums the 4 partials for ITS output frag (cols 16w..16w+15)
    f32x4 xnew = (f32x4){0.f, 0.f, 0.f, 0.f};
#pragma unroll
    for (int ww = 0; ww < 4; ww++)
        xnew += *(const f32x4*)(red + ww * 1024 + (16 * w + lr) * 16 + 4 * lg);

    // write swizzled hi/lo bf16 x_new tile (wave w owns cols 16w+lr)
    {
        int c = 16 * w + lr;
#pragma unroll
        for (int r = 0; r < 4; r++) {
            int row = 4 * lg + r;
            int idx = row * 64 + (((c >> 3) ^ (row & 7)) << 3) + (c & 7);
            float v = xnew[r];
            unsigned short hi = f2bf(v);
            tile_hi[idx] = hi;
            tile_lo[idx] = f2bf(v - bf2f(hi));
        }
    }
    __syncthreads();

    // g2 = x_new @ W_g2 (split precision); wave w computes frag f=w
    f32x4 accG = (f32x4){0.f, 0.f, 0.f, 0.f};
#pragma unroll
    for (int ks = 0; ks < 2; ks++) {
        int c0k = 32 * ks + 8 * lg;
        int idx = lr * 64 + (((c0k >> 3) ^ (lr & 7)) << 3);
        bf16x8 a_hi = *(const bf16x8*)(tile_hi + idx);
        bf16x8 a_lo = *(const bf16x8*)(tile_lo + idx);
        int off = (16 * w + lr) * 64 + c0k;
        bf16x8 b_hi = *(const bf16x8*)(Wg2T_hi + off);
        bf16x8 b_lo = *(const bf16x8*)(Wg2T_lo + off);
        accG = __builtin_amdgcn_mfma_f32_16x16x32_bf16(a_hi, b_hi, accG, 0, 0, 0);
        accG = __builtin_amdgcn_mfma_f32_16x16x32_bf16(a_hi, b_lo, accG, 0, 0, 0);
        accG = __builtin_amdgcn_mfma_f32_16x16x32_bf16(a_lo, b_hi, accG, 0, 0, 0);
    }

    // fused epilogue: gate = sigmoid(p1 + g2); out = xnew*g + xproj*(1-g)
    {
        int c = 16 * w + lr;
#pragma unroll
        for (int r = 0; r < 4; r++) {
            int n = n0 + 4 * lg + r;
            size_t g = (size_t)(b * NN + n) * 64 + c;
            float z = p1[g] + accG[r];
            float gate = 1.f / (1.f + __expf(-z));
            float xpv = xproj[g];
            out[g] = xnew[r] * gate + xpv * (1.f - gate);
        }
    }
}

extern "C" void kernel_launch(void* const* d_in, const int* in_sizes, int n_in,
                              void* d_out, int out_size, void* d_ws, size_t ws_size,
                              hipStream_t stream) {
    const float* x     = (const float*)d_in[0];
    const float* A     = (const float*)d_in[1];
    const float* W_h   = (const float*)d_in[2];
    const float* b_h   = (const float*)d_in[3];
    const float* W_fc1 = (const float*)d_in[4];
    const float* b_fc1 = (const float*)d_in[5];
    const float* W_g1  = (const float*)d_in[6];
    const float* b_g1  = (const float*)d_in[7];
    const float* W_g2  = (const float*)d_in[8];
    const float* b_g2  = (const float*)d_in[9];
    float* out = (float*)d_out;

    char* ws = (char*)d_ws;
    unsigned short* WcT_hi  = (unsigned short*)(ws);            // 32 KB
    unsigned short* WcT_lo  = (unsigned short*)(ws + 32768);    // 32 KB
    unsigned short* Wg1T_hi = (unsigned short*)(ws + 65536);    // 8 KB
    unsigned short* Wg1T_lo = (unsigned short*)(ws + 73728);    // 8 KB
    unsigned short* Wg2T_hi = (unsigned short*)(ws + 81920);    // 8 KB
    unsigned short* Wg2T_lo = (unsigned short*)(ws + 90112);    // 8 KB
    float*          bP1     = (float*)(ws + 98304);             // 256 B
    unsigned short* hT      = (unsigned short*)(ws + 131072);                      // 4 MB
    float*          xprj    = (float*)(ws + 131072 + 4194304);                     // 8 MB
    float*          p1      = (float*)(ws + 131072 + 4194304 + 8388608);           // 8 MB

    prep_k<<<97, 256, 0, stream>>>(W_h, W_fc1, W_g1, W_g2, b_g1, b_g2,
                                   WcT_hi, WcT_lo, Wg1T_hi, Wg1T_lo, Wg2T_hi, Wg2T_lo, bP1);
    k1<<<2048, 64, 0, stream>>>(x, WcT_hi, WcT_lo, Wg1T_hi, Wg1T_lo, b_h, b_fc1, bP1,
                                hT, xprj, p1);
    k2<<<2048, 256, 0, stream>>>(A, hT, Wg2T_hi, Wg2T_lo, p1, xprj, out);
}

// Round 4
// 65.520 us; speedup vs baseline: 1.4439x; 1.2799x over previous
//
#include <hip/hip_runtime.h>
#include <hip/hip_bf16.h>

#define NB 32
#define NN 1024
#define IND 128
#define HD 64

typedef float f32x4 __attribute__((ext_vector_type(4)));
typedef short bf16x8 __attribute__((ext_vector_type(8)));
typedef unsigned short ushortx4 __attribute__((ext_vector_type(4)));

union FragU { unsigned short us[8]; bf16x8 v; };

__device__ __forceinline__ unsigned short f2bf(float f) {
    union { float f; unsigned u; } x; x.f = f;
    unsigned r = x.u + 0x7FFFu + ((x.u >> 16) & 1u);  // RNE
    return (unsigned short)(r >> 16);
}
__device__ __forceinline__ float bf2f(unsigned short h) {
    union { unsigned u; float f; } x; x.u = ((unsigned)h) << 16; return x.f;
}

// ---------------- kernel 0: weight prep (transpose + hi/lo bf16 split) ------
__global__ void prep_k(const float* __restrict__ W_h, const float* __restrict__ W_fc1,
                       const float* __restrict__ W_g1, const float* __restrict__ W_g2,
                       const float* __restrict__ b_g1, const float* __restrict__ b_g2,
                       unsigned short* __restrict__ WcT_hi, unsigned short* __restrict__ WcT_lo,
                       unsigned short* __restrict__ Wg1T_hi, unsigned short* __restrict__ Wg1T_lo,
                       unsigned short* __restrict__ Wg2T_hi, unsigned short* __restrict__ Wg2T_lo,
                       float* __restrict__ biasP1) {
    int t = blockIdx.x * blockDim.x + threadIdx.x;
    if (t < 16384) {
        int o = t >> 7, k = t & 127;
        float v = (o < 64) ? W_h[k * 64 + o] : W_fc1[k * 64 + (o - 64)];
        unsigned short hi = f2bf(v);
        WcT_hi[t] = hi; WcT_lo[t] = f2bf(v - bf2f(hi));
    } else if (t < 20480) {
        int r = t - 16384; int o = r >> 6, k = r & 63;
        float v = W_g1[k * 64 + o];
        unsigned short hi = f2bf(v);
        Wg1T_hi[r] = hi; Wg1T_lo[r] = f2bf(v - bf2f(hi));
    } else if (t < 24576) {
        int r = t - 20480; int o = r >> 6, k = r & 63;
        float v = W_g2[k * 64 + o];
        unsigned short hi = f2bf(v);
        Wg2T_hi[r] = hi; Wg2T_lo[r] = f2bf(v - bf2f(hi));
    } else if (t < 24640) {
        int j = t - 24576;
        biasP1[j] = b_g1[j] + b_g2[j];
    }
}

// ---------------- kernel 1: h (-> hF frag-major bf16), x_proj (f32), p1 -----
// grid 2048 x 64 threads; block = one 16-row strip, single wave.
// hF layout (per batch, 128 KB): element (c, m) at ushort index
//   ((m>>5)*4 + (c>>4))*512 + ((c&15) + 16*((m>>3)&3))*8 + (m&7)
// so k2's fragment load is 64 lanes x 16 B contiguous.
__global__ __launch_bounds__(64) void k1(
        const float* __restrict__ x,
        const unsigned short* __restrict__ WcT_hi, const unsigned short* __restrict__ WcT_lo,
        const unsigned short* __restrict__ Wg1T_hi, const unsigned short* __restrict__ Wg1T_lo,
        const float* __restrict__ b_h, const float* __restrict__ b_fc1,
        const float* __restrict__ biasP1,
        unsigned short* __restrict__ hF, float* __restrict__ xproj,
        float* __restrict__ p1) {
    __shared__ unsigned short lds_hi[16 * 64];
    __shared__ unsigned short lds_lo[16 * 64];

    const int lane = threadIdx.x;
    const int lr = lane & 15, lg = lane >> 4;
    const int blk = blockIdx.x;
    const int b = blk >> 6;
    const int n0 = (blk & 63) * 16;

    const float* xp = x + (size_t)(b * NN + n0 + lr) * IND;

    // issue ALL x loads up-front (8 independent 16B loads)
    f32x4 xa[4][2];
#pragma unroll
    for (int ks = 0; ks < 4; ks++) {
        const f32x4* ap = (const f32x4*)(xp + 32 * ks + 8 * lg);
        xa[ks][0] = ap[0]; xa[ks][1] = ap[1];
    }

    f32x4 acc[8];
#pragma unroll
    for (int f = 0; f < 8; f++) acc[f] = (f32x4){0.f, 0.f, 0.f, 0.f};

#pragma unroll
    for (int ks = 0; ks < 4; ks++) {
        FragU ah, al;
#pragma unroll
        for (int i = 0; i < 4; i++) {
            unsigned short h0 = f2bf(xa[ks][0][i]); ah.us[i] = h0;     al.us[i]     = f2bf(xa[ks][0][i] - bf2f(h0));
            unsigned short h1 = f2bf(xa[ks][1][i]); ah.us[4 + i] = h1; al.us[4 + i] = f2bf(xa[ks][1][i] - bf2f(h1));
        }
#pragma unroll
        for (int f = 0; f < 8; f++) {
            int off = (16 * f + lr) * 128 + 32 * ks + 8 * lg;
            bf16x8 wh = *(const bf16x8*)(WcT_hi + off);
            bf16x8 wl = *(const bf16x8*)(WcT_lo + off);
            acc[f] = __builtin_amdgcn_mfma_f32_16x16x32_bf16(ah.v, wh, acc[f], 0, 0, 0);
            acc[f] = __builtin_amdgcn_mfma_f32_16x16x32_bf16(ah.v, wl, acc[f], 0, 0, 0);
            acc[f] = __builtin_amdgcn_mfma_f32_16x16x32_bf16(al.v, wh, acc[f], 0, 0, 0);
        }
    }

    const int mb = n0 + 4 * lg;          // k1's n == k2's m; multiple of 4
    const int tile = mb >> 5;
    const int lanepart = lr + 16 * ((mb >> 3) & 3);
    const int j0 = mb & 7;               // 0 or 4

    // h (frags 0..3): + bias, store to hF in k2-fragment-major order
#pragma unroll
    for (int f = 0; f < 4; f++) {
        int c = 16 * f + lr;
        float bh = b_h[c];
        ushortx4 hv;
#pragma unroll
        for (int r = 0; r < 4; r++) hv[r] = f2bf(acc[f][r] + bh);
        *(ushortx4*)(hF + (size_t)b * 65536 + (size_t)(tile * 4 + f) * 512 + lanepart * 8 + j0) = hv;
    }

    // x_proj (frags 4..7): f32 store + swizzled hi/lo bf16 to LDS
#pragma unroll
    for (int f = 4; f < 8; f++) {
        int c = 16 * (f - 4) + lr;
        float bp = b_fc1[c];
#pragma unroll
        for (int r = 0; r < 4; r++) {
            float v = acc[f][r] + bp;
            int n = mb + r;
            xproj[(size_t)(b * NN + n) * 64 + c] = v;
            int ln = 4 * lg + r;
            int idx = ln * 64 + (((c >> 3) ^ (ln & 7)) << 3) + (c & 7);
            unsigned short hi = f2bf(v);
            lds_hi[idx] = hi;
            lds_lo[idx] = f2bf(v - bf2f(hi));
        }
    }
    __syncthreads();

    // p1 = x_proj @ W_g1 + (b_g1+b_g2), split precision
    f32x4 accP[4];
#pragma unroll
    for (int f = 0; f < 4; f++) accP[f] = (f32x4){0.f, 0.f, 0.f, 0.f};
#pragma unroll
    for (int ks = 0; ks < 2; ks++) {
        int c0 = 32 * ks + 8 * lg;
        int idx = lr * 64 + (((c0 >> 3) ^ (lr & 7)) << 3);
        bf16x8 a_hi = *(const bf16x8*)(lds_hi + idx);
        bf16x8 a_lo = *(const bf16x8*)(lds_lo + idx);
#pragma unroll
        for (int f = 0; f < 4; f++) {
            int off = (16 * f + lr) * 64 + c0;
            bf16x8 b_hi = *(const bf16x8*)(Wg1T_hi + off);
            bf16x8 b_lo = *(const bf16x8*)(Wg1T_lo + off);
            accP[f] = __builtin_amdgcn_mfma_f32_16x16x32_bf16(a_hi, b_hi, accP[f], 0, 0, 0);
            accP[f] = __builtin_amdgcn_mfma_f32_16x16x32_bf16(a_hi, b_lo, accP[f], 0, 0, 0);
            accP[f] = __builtin_amdgcn_mfma_f32_16x16x32_bf16(a_lo, b_hi, accP[f], 0, 0, 0);
        }
    }
#pragma unroll
    for (int f = 0; f < 4; f++) {
        int c = 16 * f + lr;
        float bb = biasP1[c];
#pragma unroll
        for (int r = 0; r < 4; r++) {
            int n = mb + r;
            p1[(size_t)(b * NN + n) * 64 + c] = accP[f][r] + bb;
        }
    }
}

// ---------------- kernel 2: x_new = A@h ; fused gate epilogue ---------------
// grid 2048 x 64; block = one 16-row strip, single wave, full K=1024.
// Issue discipline: per iteration  convert A(it) -> MFMA(hf(it)) ->
// issue hf(it+1) -> issue A(it+4).  All waits then target the oldest
// outstanding load; A stays 4-deep in flight across hf waits.
__global__ __launch_bounds__(64) void k2(
        const float* __restrict__ A, const unsigned short* __restrict__ hF,
        const unsigned short* __restrict__ Wg2T_hi, const unsigned short* __restrict__ Wg2T_lo,
        const float* __restrict__ p1, const float* __restrict__ xproj,
        float* __restrict__ out) {
    __shared__ unsigned short tile_hi[16 * 64];
    __shared__ unsigned short tile_lo[16 * 64];

    const int lane = threadIdx.x;
    const int lr = lane & 15, lg = lane >> 4;
    const int blk = blockIdx.x;
    const int b = blk >> 6;
    const int n0 = (blk & 63) * 16;

    const float* Ap = A + (size_t)(b * NN + n0 + lr) * NN + 8 * lg;
    const unsigned short* hp = hF + (size_t)b * 65536 + lane * 8;

    f32x4 acc[4];
#pragma unroll
    for (int f = 0; f < 4; f++) acc[f] = (f32x4){0.f, 0.f, 0.f, 0.f};

    // prologue: A depth-4, hf depth-1
    f32x4 ab[4][2];
#pragma unroll
    for (int i = 0; i < 4; i++) {
        ab[i][0] = *(const f32x4*)(Ap + 32 * i);
        ab[i][1] = *(const f32x4*)(Ap + 32 * i + 4);
    }
    bf16x8 hb[2][4];
#pragma unroll
    for (int f = 0; f < 4; f++) hb[0][f] = *(const bf16x8*)(hp + f * 512);

#pragma unroll
    for (int it = 0; it < 32; ++it) {
        // convert A(it)
        FragU au;
        f32x4 c0 = ab[it & 3][0], c1 = ab[it & 3][1];
#pragma unroll
        for (int i = 0; i < 4; i++) { au.us[i] = f2bf(c0[i]); au.us[4 + i] = f2bf(c1[i]); }
        // MFMA with hf(it)
#pragma unroll
        for (int f = 0; f < 4; f++)
            acc[f] = __builtin_amdgcn_mfma_f32_16x16x32_bf16(au.v, hb[it & 1][f], acc[f], 0, 0, 0);
        // issue hf(it+1)  (1 KB contiguous per load)
        if (it < 31) {
#pragma unroll
            for (int f = 0; f < 4; f++)
                hb[(it + 1) & 1][f] = *(const bf16x8*)(hp + (size_t)((it + 1) * 4 + f) * 512);
        }
        // issue A(it+4)
        if (it < 28) {
            ab[it & 3][0] = *(const f32x4*)(Ap + (it + 4) * 32);
            ab[it & 3][1] = *(const f32x4*)(Ap + (it + 4) * 32 + 4);
        }
    }

    // transpose x_new hi/lo (bf16) into swizzled LDS tile
#pragma unroll
    for (int f = 0; f < 4; f++) {
        int c = 16 * f + lr;
#pragma unroll
        for (int r = 0; r < 4; r++) {
            int row = 4 * lg + r;
            int idx = row * 64 + (((c >> 3) ^ (row & 7)) << 3) + (c & 7);
            float v = acc[f][r];
            unsigned short hi = f2bf(v);
            tile_hi[idx] = hi;
            tile_lo[idx] = f2bf(v - bf2f(hi));
        }
    }
    __syncthreads();

    // g2 = x_new @ W_g2 (split precision)
    f32x4 accG[4];
#pragma unroll
    for (int f = 0; f < 4; f++) accG[f] = (f32x4){0.f, 0.f, 0.f, 0.f};
#pragma unroll
    for (int ks = 0; ks < 2; ks++) {
        int c0k = 32 * ks + 8 * lg;
        int idx = lr * 64 + (((c0k >> 3) ^ (lr & 7)) << 3);
        bf16x8 a_hi = *(const bf16x8*)(tile_hi + idx);
        bf16x8 a_lo = *(const bf16x8*)(tile_lo + idx);
#pragma unroll
        for (int f = 0; f < 4; f++) {
            int off = (16 * f + lr) * 64 + c0k;
            bf16x8 b_hi = *(const bf16x8*)(Wg2T_hi + off);
            bf16x8 b_lo = *(const bf16x8*)(Wg2T_lo + off);
            accG[f] = __builtin_amdgcn_mfma_f32_16x16x32_bf16(a_hi, b_hi, accG[f], 0, 0, 0);
            accG[f] = __builtin_amdgcn_mfma_f32_16x16x32_bf16(a_hi, b_lo, accG[f], 0, 0, 0);
            accG[f] = __builtin_amdgcn_mfma_f32_16x16x32_bf16(a_lo, b_hi, accG[f], 0, 0, 0);
        }
    }

    // fused epilogue: gate = sigmoid(p1 + g2); out = xnew*g + xproj*(1-g)
#pragma unroll
    for (int f = 0; f < 4; f++) {
        int c = 16 * f + lr;
#pragma unroll
        for (int r = 0; r < 4; r++) {
            int n = n0 + 4 * lg + r;
            size_t g = (size_t)(b * NN + n) * 64 + c;
            float z = p1[g] + accG[f][r];
            float gate = 1.f / (1.f + __expf(-z));
            float xpv = xproj[g];
            out[g] = acc[f][r] * gate + xpv * (1.f - gate);
        }
    }
}

extern "C" void kernel_launch(void* const* d_in, const int* in_sizes, int n_in,
                              void* d_out, int out_size, void* d_ws, size_t ws_size,
                              hipStream_t stream) {
    const float* x     = (const float*)d_in[0];
    const float* A     = (const float*)d_in[1];
    const float* W_h   = (const float*)d_in[2];
    const float* b_h   = (const float*)d_in[3];
    const float* W_fc1 = (const float*)d_in[4];
    const float* b_fc1 = (const float*)d_in[5];
    const float* W_g1  = (const float*)d_in[6];
    const float* b_g1  = (const float*)d_in[7];
    const float* W_g2  = (const float*)d_in[8];
    const float* b_g2  = (const float*)d_in[9];
    float* out = (float*)d_out;

    char* ws = (char*)d_ws;
    unsigned short* WcT_hi  = (unsigned short*)(ws);            // 32 KB
    unsigned short* WcT_lo  = (unsigned short*)(ws + 32768);    // 32 KB
    unsigned short* Wg1T_hi = (unsigned short*)(ws + 65536);    // 8 KB
    unsigned short* Wg1T_lo = (unsigned short*)(ws + 73728);    // 8 KB
    unsigned short* Wg2T_hi = (unsigned short*)(ws + 81920);    // 8 KB
    unsigned short* Wg2T_lo = (unsigned short*)(ws + 90112);    // 8 KB
    float*          bP1     = (float*)(ws + 98304);             // 256 B
    unsigned short* hF      = (unsigned short*)(ws + 131072);                      // 4 MB
    float*          xprj    = (float*)(ws + 131072 + 4194304);                     // 8 MB
    float*          p1      = (float*)(ws + 131072 + 4194304 + 8388608);           // 8 MB

    prep_k<<<97, 256, 0, stream>>>(W_h, W_fc1, W_g1, W_g2, b_g1, b_g2,
                                   WcT_hi, WcT_lo, Wg1T_hi, Wg1T_lo, Wg2T_hi, Wg2T_lo, bP1);
    k1<<<2048, 64, 0, stream>>>(x, WcT_hi, WcT_lo, Wg1T_hi, Wg1T_lo, b_h, b_fc1, bP1,
                                hF, xprj, p1);
    k2<<<2048, 64, 0, stream>>>(A, hF, Wg2T_hi, Wg2T_lo, p1, xprj, out);
}